// Round 1
// baseline (271.455 us; speedup 1.0000x reference)
//
#include <hip/hip_runtime.h>
#include <math.h>

#define B_TOTAL   16384
#define N_DENSE   13
#define N_TABLES  26
#define V_ROWS    1000000
#define E_DIM     2

__global__ __launch_bounds__(64) void dlrm_fused_kernel(
    const float* __restrict__ x_dense,   // [B,13]
    const int*   __restrict__ x_cat,     // [B,26]
    const float* __restrict__ emb,       // [26,1000000,2]
    const float* __restrict__ bw1,       // [13,3]
    const float* __restrict__ bb1,       // [3]
    const float* __restrict__ bw2,       // [3,2]
    const float* __restrict__ bb2,       // [2]
    const float* __restrict__ tw1,       // [54,4]
    const float* __restrict__ tb1,       // [4]
    const float* __restrict__ tw2,       // [4,2]
    const float* __restrict__ tb2,       // [2]
    const float* __restrict__ tw3,       // [2,1]
    const float* __restrict__ tb3,       // [1]
    float*       __restrict__ out)       // [B,1]
{
    const int b = blockIdx.x * blockDim.x + threadIdx.x;
    if (b >= B_TOTAL) return;

    // ---- issue the 26 independent embedding gathers as early as possible ----
    float ev[2 * N_TABLES];
    {
        const long long cbase = (long long)b * N_TABLES;
        #pragma unroll
        for (int t = 0; t < N_TABLES; ++t) {
            const int idx = x_cat[cbase + t];
            const float2 v = *reinterpret_cast<const float2*>(
                emb + ((size_t)t * V_ROWS + (size_t)idx) * E_DIM);
            ev[2 * t]     = v.x;
            ev[2 * t + 1] = v.y;
        }
    }

    // ---- bottom MLP: 13 -> 3 -> 2, relu ----
    float xd[N_DENSE];
    {
        const long long dbase = (long long)b * N_DENSE;
        #pragma unroll
        for (int i = 0; i < N_DENSE; ++i) xd[i] = x_dense[dbase + i];
    }
    float d1[3];
    #pragma unroll
    for (int j = 0; j < 3; ++j) {
        float acc = bb1[j];
        #pragma unroll
        for (int i = 0; i < N_DENSE; ++i) acc = fmaf(xd[i], bw1[i * 3 + j], acc);
        d1[j] = fmaxf(acc, 0.0f);
    }
    float d2[2];
    #pragma unroll
    for (int j = 0; j < 2; ++j) {
        float acc = bb2[j];
        #pragma unroll
        for (int i = 0; i < 3; ++i) acc = fmaf(d1[i], bw2[i * 2 + j], acc);
        d2[j] = fmaxf(acc, 0.0f);
    }

    // ---- top MLP input x = concat(d2[2], ev[52]) -> 54 ----
    // h1 = relu(x @ tw1 + tb1), tw1 is [54,4] row-major
    float h1[4];
    #pragma unroll
    for (int j = 0; j < 4; ++j) {
        float acc = tb1[j];
        acc = fmaf(d2[0], tw1[0 * 4 + j], acc);
        acc = fmaf(d2[1], tw1[1 * 4 + j], acc);
        #pragma unroll
        for (int i = 0; i < 2 * N_TABLES; ++i)
            acc = fmaf(ev[i], tw1[(2 + i) * 4 + j], acc);
        h1[j] = fmaxf(acc, 0.0f);
    }
    float h2[2];
    #pragma unroll
    for (int j = 0; j < 2; ++j) {
        float acc = tb2[j];
        #pragma unroll
        for (int i = 0; i < 4; ++i) acc = fmaf(h1[i], tw2[i * 2 + j], acc);
        h2[j] = fmaxf(acc, 0.0f);
    }
    float z = tb3[0];
    z = fmaf(h2[0], tw3[0], z);
    z = fmaf(h2[1], tw3[1], z);

    out[b] = 1.0f / (1.0f + expf(-z));
}

extern "C" void kernel_launch(void* const* d_in, const int* in_sizes, int n_in,
                              void* d_out, int out_size, void* d_ws, size_t ws_size,
                              hipStream_t stream) {
    const float* x_dense = (const float*)d_in[0];
    const int*   x_cat   = (const int*)  d_in[1];
    const float* emb     = (const float*)d_in[2];
    const float* bw1     = (const float*)d_in[3];
    const float* bb1     = (const float*)d_in[4];
    const float* bw2     = (const float*)d_in[5];
    const float* bb2     = (const float*)d_in[6];
    const float* tw1     = (const float*)d_in[7];
    const float* tb1     = (const float*)d_in[8];
    const float* tw2     = (const float*)d_in[9];
    const float* tb2     = (const float*)d_in[10];
    const float* tw3     = (const float*)d_in[11];
    const float* tb3     = (const float*)d_in[12];
    float* out = (float*)d_out;

    const int block = 64;                      // 1 wave/block -> 256 blocks, one per CU
    const int grid  = (B_TOTAL + block - 1) / block;
    dlrm_fused_kernel<<<grid, block, 0, stream>>>(
        x_dense, x_cat, emb, bw1, bb1, bw2, bb2,
        tw1, tb1, tw2, tb2, tw3, tb3, out);
}